// Round 6
// baseline (854.626 us; speedup 1.0000x reference)
//
#include <hip/hip_runtime.h>

#define NN 50000
#define NE 800000
#define NT64 12500   // 800000 / 64 edge tiles
#define TPB2 8       // 64-edge tiles per block
#define NBLK 1563    // ceil(12500/8)
#define WROWS 48     // LDS accumulation window rows (block src span ~34)

typedef _Float16 half8 __attribute__((ext_vector_type(8)));
typedef float f32x4 __attribute__((ext_vector_type(4)));

__device__ __forceinline__ float sigm(float x) { return 1.0f / (1.0f + __expf(-x)); }

// ---------- prep: W (f32 [k][n] 128x128) -> W^T (f16 [n][k]) in ws ----------
__global__ void prepw_kernel(const float* __restrict__ w0, const float* __restrict__ w1,
                             const float* __restrict__ w2, _Float16* __restrict__ wt) {
  const float* w = blockIdx.x == 0 ? w0 : (blockIdx.x == 1 ? w1 : w2);
  _Float16* o = wt + blockIdx.x * 16384;
  int t = threadIdx.x;
  for (int it = 0; it < 64; ++it) {
    int flat = it * 256 + t;
    int k = flat >> 7, n = flat & 127;
    o[n * 128 + k] = (_Float16)w[flat];
  }
}

// ---------- degree histogram ----------
__global__ void hist_kernel(const int* __restrict__ eidx, unsigned* __restrict__ cnt) {
  int e = blockIdx.x * 256 + threadIdx.x;
  if (e < NE) atomicAdd(&cnt[eidx[2 * e]], 1u);
}

// ---------- exclusive prefix scan of cnt -> cursor (one 1024-thread block) ----------
__global__ __launch_bounds__(1024) void scan_kernel(const unsigned* __restrict__ cnt,
                                                    unsigned* __restrict__ cursor) {
  __shared__ unsigned part[1024];
  const int t = threadIdx.x;
  const int CH = 49;                  // 1024*49 = 50176 >= NN
  int base = t * CH;
  unsigned s = 0;
  for (int i = 0; i < CH; ++i) { int j = base + i; if (j < NN) s += cnt[j]; }
  part[t] = s;
  __syncthreads();
  for (int off = 1; off < 1024; off <<= 1) {
    unsigned v = (t >= off) ? part[t - off] : 0u;
    __syncthreads();
    part[t] += v;
    __syncthreads();
  }
  unsigned run = (t > 0) ? part[t - 1] : 0u;
  for (int i = 0; i < CH; ++i) {
    int j = base + i;
    if (j < NN) { cursor[j] = run; run += cnt[j]; }
  }
}

// ---------- counting-sort scatter: one int4(src,dst,eid,0) per slot ----------
__global__ void scatter_kernel(const int* __restrict__ eidx, unsigned* __restrict__ cursor,
                               int4* __restrict__ sedge) {
  int e = blockIdx.x * 256 + threadIdx.x;
  if (e >= NE) return;
  int s = eidx[2 * e], d = eidx[2 * e + 1];
  unsigned pos = atomicAdd(&cursor[s], 1u);
  sedge[pos] = make_int4(s, d, e, 0);
}

// ---------- node GEMM: nh16 = f16(nf @ Wn + bn) ----------
__global__ __launch_bounds__(512, 2) void node_kernel(
    const float* __restrict__ nf, const _Float16* __restrict__ wnT,
    const float* __restrict__ bnp, _Float16* __restrict__ nh16) {
  __shared__ __align__(16) char wl[32768];
  __shared__ __align__(16) char tl[65536];

  const int t = threadIdx.x;
  const int lane = t & 63;
  const int wave = t >> 6;
  const int wm = wave >> 2;
  const int wn = wave & 3;

  for (int it = 0; it < 4; ++it) {
    int h8 = it * 512 + t;
    int n = h8 >> 4, k8 = h8 & 15;
    half8 v = *(const half8*)(wnT + n * 128 + k8 * 8);
    *(half8*)(wl + ((n * 256 + k8 * 16) ^ ((n & 7) << 4))) = v;
  }

  const int row0 = blockIdx.x * 256;
  for (int it = 0; it < 8; ++it) {
    int idx8 = it * 512 + t;
    int row = idx8 >> 4, col8 = idx8 & 15;
    int grow = row0 + row;
    half8 h;
    if (grow < NN) {
      const float4* s = (const float4*)(nf + (size_t)grow * 128 + col8 * 8);
      float4 a = s[0], b = s[1];
      h[0] = (_Float16)a.x; h[1] = (_Float16)a.y; h[2] = (_Float16)a.z; h[3] = (_Float16)a.w;
      h[4] = (_Float16)b.x; h[5] = (_Float16)b.y; h[6] = (_Float16)b.z; h[7] = (_Float16)b.w;
    } else {
#pragma unroll
      for (int j = 0; j < 8; ++j) h[j] = (_Float16)0.0f;
    }
    *(half8*)(tl + ((row * 256 + col8 * 16) ^ ((row & 7) << 4))) = h;
  }
  __syncthreads();

  const int c0 = wn * 32 + (lane & 15);
  const int arow = wm * 128 + (lane & 15);
  const int akb = (lane >> 4) * 16;

  f32x4 acc[8][2] = {};
#pragma unroll
  for (int ks = 0; ks < 4; ++ks) {
    int kb = ks * 64 + akb;
    half8 B0 = *(half8*)(wl + c0 * 256 + (kb ^ ((c0 & 7) << 4)));
    half8 B1 = *(half8*)(wl + (c0 + 16) * 256 + (kb ^ ((c0 & 7) << 4)));
#pragma unroll
    for (int mi = 0; mi < 8; ++mi) {
      int r = arow + mi * 16;
      half8 A = *(half8*)(tl + r * 256 + (kb ^ ((r & 7) << 4)));
      acc[mi][0] = __builtin_amdgcn_mfma_f32_16x16x32_f16(A, B0, acc[mi][0], 0, 0, 0);
      acc[mi][1] = __builtin_amdgcn_mfma_f32_16x16x32_f16(A, B1, acc[mi][1], 0, 0, 0);
    }
  }

  const float b0 = bnp[c0], b1 = bnp[c0 + 16];
#pragma unroll
  for (int mi = 0; mi < 8; ++mi) {
#pragma unroll
    for (int r = 0; r < 4; ++r) {
      int grow = row0 + wm * 128 + mi * 16 + (lane >> 4) * 4 + r;
      if (grow < NN) {
        nh16[(size_t)grow * 128 + c0] = (_Float16)(acc[mi][0][r] + b0);
        nh16[(size_t)grow * 128 + c0 + 16] = (_Float16)(acc[mi][1][r] + b1);
      }
    }
  }
}

// ---------- fused edge kernel: 256 threads, 64-edge tiles, 3 blocks/CU ----------
// gather ef rows -> f16 LDS tile -> dual GEMM (B from L2) -> messages (f16 nh
// gather) -> f16 msg tile -> run-length reduce into LDS f32 window -> one
// atomic flush per (block,src).
__global__ __launch_bounds__(256, 3) void edge_kernel(
    const float* __restrict__ ef, const int4* __restrict__ sedge,
    const _Float16* __restrict__ wgT, const _Float16* __restrict__ wfT,
    const float* __restrict__ bgp, const float* __restrict__ bfp,
    const _Float16* __restrict__ nh16, float* __restrict__ sums) {
  __shared__ __align__(16) char tl[16384];       // 64 rows x 256B swizzled / msg tile
  __shared__ float win[WROWS][128];              // 24KB f32 accumulation window
  __shared__ int ls[64], ld[64], le[64];
  __shared__ int sh_wbase;

  const int t = threadIdx.x;
  const int lane = t & 63;
  const int wn = t >> 6;      // wave 0..3 : 32-col group (gate AND filt)
  const int q = lane >> 4;    // 0..3

  const int tstart = blockIdx.x * TPB2;
  int tend = tstart + TPB2; if (tend > NT64) tend = NT64;
  if (tstart >= NT64) return;

  // zero window; fetch window base src
  {
    float* w = &win[0][0];
    for (int i = t; i < WROWS * 128; i += 256) w[i] = 0.0f;
  }
  if (t == 0) sh_wbase = sedge[(size_t)tstart * 64].x;
  __syncthreads();
  const int wbase = sh_wbase;

  const int c0 = wn * 32 + (lane & 15);
  const float bg0 = bgp[c0], bg1 = bgp[c0 + 16];
  const float bf0 = bfp[c0], bf1 = bfp[c0 + 16];
  const int boff = q * 8;

  for (int tile = tstart; tile < tend; ++tile) {
    if (t < 64) {
      int4 v = sedge[(size_t)tile * 64 + t];
      ls[t] = v.x; ld[t] = v.y; le[t] = v.z;
    }
    __syncthreads();

    // stage 64 gathered ef rows fp32 -> f16, swizzled (16 threads/row)
#pragma unroll
    for (int it = 0; it < 4; ++it) {
      int idx8 = it * 256 + t;            // 0..1023, 8 floats each
      int row = idx8 >> 4, col8 = idx8 & 15;
      const float4* s = (const float4*)(ef + (size_t)le[row] * 128 + col8 * 8);
      float4 a = s[0], b = s[1];
      half8 h;
      h[0] = (_Float16)a.x; h[1] = (_Float16)a.y; h[2] = (_Float16)a.z; h[3] = (_Float16)a.w;
      h[4] = (_Float16)b.x; h[5] = (_Float16)b.y; h[6] = (_Float16)b.z; h[7] = (_Float16)b.w;
      *(half8*)(tl + ((row * 256 + col8 * 16) ^ ((row & 7) << 4))) = h;
    }
    __syncthreads();

    // dual GEMM: 64 edges x {32 gate cols + 32 filt cols} per wave, B from L2
    f32x4 acc[4][4] = {};
#pragma unroll
    for (int ks = 0; ks < 4; ++ks) {
      const _Float16* bg = wgT + ks * 32 + boff;
      const _Float16* bff = wfT + ks * 32 + boff;
      half8 Bg0 = *(const half8*)(bg + (size_t)c0 * 128);
      half8 Bg1 = *(const half8*)(bg + (size_t)(c0 + 16) * 128);
      half8 Bf0 = *(const half8*)(bff + (size_t)c0 * 128);
      half8 Bf1 = *(const half8*)(bff + (size_t)(c0 + 16) * 128);
#pragma unroll
      for (int mi = 0; mi < 4; ++mi) {
        int r = mi * 16 + (lane & 15);
        half8 A = *(half8*)(tl + ((r * 256 + ks * 64 + q * 16) ^ ((r & 7) << 4)));
        acc[mi][0] = __builtin_amdgcn_mfma_f32_16x16x32_f16(A, Bg0, acc[mi][0], 0, 0, 0);
        acc[mi][1] = __builtin_amdgcn_mfma_f32_16x16x32_f16(A, Bg1, acc[mi][1], 0, 0, 0);
        acc[mi][2] = __builtin_amdgcn_mfma_f32_16x16x32_f16(A, Bf0, acc[mi][2], 0, 0, 0);
        acc[mi][3] = __builtin_amdgcn_mfma_f32_16x16x32_f16(A, Bf1, acc[mi][3], 0, 0, 0);
      }
    }
    __syncthreads();   // all waves done reading A-tile -> reuse tl for messages

    // messages = sigm(gate)*filt*nh16[dst] -> f16 msg tile (swizzled by edge row)
#pragma unroll
    for (int mi = 0; mi < 4; ++mi) {
#pragma unroll
      for (int r = 0; r < 4; ++r) {
        int el = mi * 16 + q * 4 + r;
        int dstn = ld[el];
        float n0 = (float)nh16[(size_t)dstn * 128 + c0];
        float n1 = (float)nh16[(size_t)dstn * 128 + c0 + 16];
        float m0 = sigm(acc[mi][0][r] + bg0) * (acc[mi][2][r] + bf0) * n0;
        float m1 = sigm(acc[mi][1][r] + bg1) * (acc[mi][3][r] + bf1) * n1;
        *(_Float16*)(tl + el * 256 + ((c0 * 2) ^ ((el & 7) << 4))) = (_Float16)m0;
        *(_Float16*)(tl + el * 256 + (((c0 + 16) * 2) ^ ((el & 7) << 4))) = (_Float16)m1;
      }
    }
    __syncthreads();

    // column-wise run-length reduce -> LDS window (rare overflow -> global atomic)
    {
      const int col = t & 127;
      const int e0 = (t >> 7) * 32;    // 2 groups x 32 edges
      float a = 0.0f;
      int cur = ls[e0];
#pragma unroll 8
      for (int k = 0; k < 32; ++k) {
        int e = e0 + k;
        int scur = ls[e];
        if (scur != cur) {
          int row = cur - wbase;
          if (row < WROWS) atomicAdd(&win[row][col], a);
          else atomicAdd(&sums[(size_t)cur * 128 + col], a);
          a = 0.0f; cur = scur;
        }
        a += (float)*(const _Float16*)(tl + e * 256 + ((col * 2) ^ ((e & 7) << 4)));
      }
      int row = cur - wbase;
      if (row < WROWS) atomicAdd(&win[row][col], a);
      else atomicAdd(&sums[(size_t)cur * 128 + col], a);
    }
    __syncthreads();   // reduce done before next tile overwrites tl/ls
  }

  // single flush per (block, src row): skip exact-zero cells
  for (int i = t; i < WROWS * 128; i += 256) {
    float v = win[i >> 7][i & 127];
    if (v != 0.0f) atomicAdd(&sums[(size_t)(wbase + (i >> 7)) * 128 + (i & 127)], v);
  }
}

// ---------- finalize: out = relu(bn(nh16 + sums/cnt)) ----------
__global__ void finalize_kernel(const _Float16* __restrict__ nh16, const float* __restrict__ sums,
                                const unsigned* __restrict__ cnt,
                                const float* __restrict__ gamma, const float* __restrict__ beta,
                                const float* __restrict__ mean, const float* __restrict__ var,
                                float* __restrict__ out) {
  int i = blockIdx.x * 256 + threadIdx.x;     // float4 index
  if (i >= NN * 32) return;
  int row = i >> 5;
  int c = (i & 31) * 4;
  float cf = (float)cnt[row];
  float inv = cf > 0.0f ? 1.0f / cf : 0.0f;
  float4 s = ((const float4*)sums)[i];
  const _Float16* h = nh16 + (size_t)row * 128 + c;
  float h0 = (float)h[0], h1 = (float)h[1], h2 = (float)h[2], h3 = (float)h[3];
  float4 o;
#define BN1(comp, hv, j)                                                        \
  {                                                                             \
    float sc = rsqrtf(var[c + j] + 0.001f) * gamma[c + j];                      \
    float v = (hv + s.comp * inv - mean[c + j]) * sc + beta[c + j];             \
    o.comp = fmaxf(v, 0.0f);                                                    \
  }
  BN1(x, h0, 0) BN1(y, h1, 1) BN1(z, h2, 2) BN1(w, h3, 3)
#undef BN1
  ((float4*)out)[i] = o;
}

extern "C" void kernel_launch(void* const* d_in, const int* in_sizes, int n_in,
                              void* d_out, int out_size, void* d_ws, size_t ws_size,
                              hipStream_t stream) {
  const float* nf    = (const float*)d_in[0];
  const float* ef    = (const float*)d_in[1];
  const float* Wn    = (const float*)d_in[2];
  const float* bn    = (const float*)d_in[3];
  const float* Wg    = (const float*)d_in[4];
  const float* bg    = (const float*)d_in[5];
  const float* Wf    = (const float*)d_in[6];
  const float* bf    = (const float*)d_in[7];
  const float* gamma = (const float*)d_in[8];
  const float* beta  = (const float*)d_in[9];
  const float* mean  = (const float*)d_in[10];
  const float* var   = (const float*)d_in[11];
  const int*   eidx  = (const int*)d_in[12];
  float* out = (float*)d_out;
  char* ws = (char*)d_ws;

  _Float16* nh16   = (_Float16*)(ws + 0);            // 12,800,000
  float*    sums   = (float*)(ws + 12800000);        // 25,600,000
  unsigned* cnt    = (unsigned*)(ws + 38400000);     //    200,000
  unsigned* cursor = (unsigned*)(ws + 38600000);     //    200,000
  _Float16* wt     = (_Float16*)(ws + 38800000);     //     98,304
  int4*     sedge  = (int4*)(ws + 38900000);         // 12,800,000 (16B aligned)

  hipMemsetAsync(sums, 0, 25600000 + 200000, stream);  // sums + cnt (contiguous)

  prepw_kernel<<<3, 256, 0, stream>>>(Wn, Wg, Wf, wt);
  hist_kernel<<<NE / 256, 256, 0, stream>>>(eidx, cnt);
  scan_kernel<<<1, 1024, 0, stream>>>(cnt, cursor);
  scatter_kernel<<<NE / 256, 256, 0, stream>>>(eidx, cursor, sedge);
  node_kernel<<<(NN + 255) / 256, 512, 0, stream>>>(nf, wt, bn, nh16);
  edge_kernel<<<NBLK, 256, 0, stream>>>(ef, sedge, wt + 16384, wt + 32768,
                                        bg, bf, nh16, sums);
  finalize_kernel<<<NN * 32 / 256, 256, 0, stream>>>(nh16, sums, cnt, gamma, beta, mean, var, out);
}

// Round 7
// 455.896 us; speedup vs baseline: 1.8746x; 1.8746x over previous
//
#include <hip/hip_runtime.h>

#define NN 50000
#define NE 800000
#define NT 12500     // 64-edge tiles
#define E1B 1788     // E1 blocks
#define E1T 7        // tiles per E1 block (1788*7 >= 12500)

typedef _Float16 half8 __attribute__((ext_vector_type(8)));
typedef _Float16 half2v __attribute__((ext_vector_type(2)));
typedef float f32x4 __attribute__((ext_vector_type(4)));

__device__ __forceinline__ float sigm(float x) { return 1.0f / (1.0f + __expf(-x)); }

// ---------- prep: W (f32 [k][n] 128x128) -> W^T (f16 [n][k]) in ws ----------
__global__ void prepw_kernel(const float* __restrict__ w0, const float* __restrict__ w1,
                             const float* __restrict__ w2, _Float16* __restrict__ wt) {
  const float* w = blockIdx.x == 0 ? w0 : (blockIdx.x == 1 ? w1 : w2);
  _Float16* o = wt + blockIdx.x * 16384;
  int t = threadIdx.x;
  for (int it = 0; it < 64; ++it) {
    int flat = it * 256 + t;
    int k = flat >> 7, n = flat & 127;
    o[n * 128 + k] = (_Float16)w[flat];
  }
}

// ---------- degree histogram ----------
__global__ void hist_kernel(const int* __restrict__ eidx, unsigned* __restrict__ cnt) {
  int e = blockIdx.x * 256 + threadIdx.x;
  if (e < NE) atomicAdd(&cnt[eidx[2 * e]], 1u);
}

// ---------- exclusive prefix scan: cnt -> cursor & cstart ----------
__global__ __launch_bounds__(1024) void scan_kernel(const unsigned* __restrict__ cnt,
                                                    unsigned* __restrict__ cursor,
                                                    unsigned* __restrict__ cstart) {
  __shared__ unsigned part[1024];
  const int t = threadIdx.x;
  const int CH = 49;                  // 1024*49 = 50176 >= NN
  int base = t * CH;
  unsigned s = 0;
  for (int i = 0; i < CH; ++i) { int j = base + i; if (j < NN) s += cnt[j]; }
  part[t] = s;
  __syncthreads();
  for (int off = 1; off < 1024; off <<= 1) {
    unsigned v = (t >= off) ? part[t - off] : 0u;
    __syncthreads();
    part[t] += v;
    __syncthreads();
  }
  unsigned run = (t > 0) ? part[t - 1] : 0u;
  for (int i = 0; i < CH; ++i) {
    int j = base + i;
    if (j < NN) { cursor[j] = run; cstart[j] = run; run += cnt[j]; }
  }
}

// ---------- counting-sort scatter: (dst, eid) sorted by src ----------
__global__ void scatter_kernel(const int* __restrict__ eidx, unsigned* __restrict__ cursor,
                               int2* __restrict__ sed) {
  int e = blockIdx.x * 256 + threadIdx.x;
  if (e >= NE) return;
  int s = eidx[2 * e], d = eidx[2 * e + 1];
  unsigned pos = atomicAdd(&cursor[s], 1u);
  sed[pos] = make_int2(d, e);
}

// ---------- node GEMM: nh16 = f16(nf @ Wn + bn) ----------
__global__ __launch_bounds__(512, 2) void node_kernel(
    const float* __restrict__ nf, const _Float16* __restrict__ wnT,
    const float* __restrict__ bnp, _Float16* __restrict__ nh16) {
  __shared__ __align__(16) char wl[32768];
  __shared__ __align__(16) char tl[65536];

  const int t = threadIdx.x;
  const int lane = t & 63;
  const int wave = t >> 6;
  const int wm = wave >> 2;
  const int wn = wave & 3;

  for (int it = 0; it < 4; ++it) {
    int h8 = it * 512 + t;
    int n = h8 >> 4, k8 = h8 & 15;
    half8 v = *(const half8*)(wnT + n * 128 + k8 * 8);
    *(half8*)(wl + ((n * 256 + k8 * 16) ^ ((n & 7) << 4))) = v;
  }

  const int row0 = blockIdx.x * 256;
  for (int it = 0; it < 8; ++it) {
    int idx8 = it * 512 + t;
    int row = idx8 >> 4, col8 = idx8 & 15;
    int grow = row0 + row;
    half8 h;
    if (grow < NN) {
      const float4* s = (const float4*)(nf + (size_t)grow * 128 + col8 * 8);
      float4 a = s[0], b = s[1];
      h[0] = (_Float16)a.x; h[1] = (_Float16)a.y; h[2] = (_Float16)a.z; h[3] = (_Float16)a.w;
      h[4] = (_Float16)b.x; h[5] = (_Float16)b.y; h[6] = (_Float16)b.z; h[7] = (_Float16)b.w;
    } else {
#pragma unroll
      for (int j = 0; j < 8; ++j) h[j] = (_Float16)0.0f;
    }
    *(half8*)(tl + ((row * 256 + col8 * 16) ^ ((row & 7) << 4))) = h;
  }
  __syncthreads();

  const int c0 = wn * 32 + (lane & 15);
  const int arow = wm * 128 + (lane & 15);
  const int akb = (lane >> 4) * 16;

  f32x4 acc[8][2] = {};
#pragma unroll
  for (int ks = 0; ks < 4; ++ks) {
    int kb = ks * 64 + akb;
    half8 B0 = *(half8*)(wl + c0 * 256 + (kb ^ ((c0 & 7) << 4)));
    half8 B1 = *(half8*)(wl + (c0 + 16) * 256 + (kb ^ ((c0 & 7) << 4)));
#pragma unroll
    for (int mi = 0; mi < 8; ++mi) {
      int r = arow + mi * 16;
      half8 A = *(half8*)(tl + r * 256 + (kb ^ ((r & 7) << 4)));
      acc[mi][0] = __builtin_amdgcn_mfma_f32_16x16x32_f16(A, B0, acc[mi][0], 0, 0, 0);
      acc[mi][1] = __builtin_amdgcn_mfma_f32_16x16x32_f16(A, B1, acc[mi][1], 0, 0, 0);
    }
  }

  const float b0 = bnp[c0], b1 = bnp[c0 + 16];
#pragma unroll
  for (int mi = 0; mi < 8; ++mi) {
#pragma unroll
    for (int r = 0; r < 4; ++r) {
      int grow = row0 + wm * 128 + mi * 16 + (lane >> 4) * 4 + r;
      if (grow < NN) {
        nh16[(size_t)grow * 128 + c0] = (_Float16)(acc[mi][0][r] + b0);
        nh16[(size_t)grow * 128 + c0 + 16] = (_Float16)(acc[mi][1][r] + b1);
      }
    }
  }
}

// ---------- E1: pure-streaming dual GEMM, B in registers, 1 barrier/tile ----------
// P[e] = sigm(ef[e]@Wg+bg) * (ef[e]@Wf+bf)  (f16, original edge order)
__global__ __launch_bounds__(512, 4) void e1_kernel(
    const float* __restrict__ ef,
    const _Float16* __restrict__ wgT, const _Float16* __restrict__ wfT,
    const float* __restrict__ bgp, const float* __restrict__ bfp,
    _Float16* __restrict__ P) {
  __shared__ __align__(16) char tl[2][16384];   // 64 edges x 128 f16, swizzled, dbuf

  const int t = threadIdx.x;
  const int lane = t & 63;
  const int w = t >> 6;        // wave 0..7 -> 16-col slice
  const int lc = lane & 15;
  const int q = lane >> 4;     // 0..3

  // B fragments in registers, loaded ONCE per block
  const int col = w * 16 + lc;
  half8 Bg[4], Bf[4];
#pragma unroll
  for (int ks = 0; ks < 4; ++ks) {
    Bg[ks] = *(const half8*)(wgT + (size_t)col * 128 + ks * 32 + q * 8);
    Bf[ks] = *(const half8*)(wfT + (size_t)col * 128 + ks * 32 + q * 8);
  }
  const float bgv = bgp[col], bfv = bfp[col];

  int first = blockIdx.x * E1T;
  int last = first + E1T; if (last > NT) last = NT;
  if (first >= NT) return;

  float4 r0a, r0b, r1a, r1b;   // staging registers (2x 8 floats)

#define LOADR(tile)                                                              \
  {                                                                              \
    const float* b0_ = ef + (size_t)((tile) * 64 + (t >> 4)) * 128 + (t & 15) * 8; \
    r0a = *(const float4*)b0_; r0b = *(const float4*)(b0_ + 4);                  \
    const float* b1_ = b0_ + (size_t)32 * 128;                                   \
    r1a = *(const float4*)b1_; r1b = *(const float4*)(b1_ + 4);                  \
  }

#define WRITEB(bf_)                                                              \
  {                                                                              \
    int row_ = t >> 4, c16_ = (t & 15) * 16;                                     \
    half8 h_;                                                                    \
    h_[0]=(_Float16)r0a.x; h_[1]=(_Float16)r0a.y; h_[2]=(_Float16)r0a.z; h_[3]=(_Float16)r0a.w; \
    h_[4]=(_Float16)r0b.x; h_[5]=(_Float16)r0b.y; h_[6]=(_Float16)r0b.z; h_[7]=(_Float16)r0b.w; \
    *(half8*)(tl[bf_] + ((row_ * 256 + c16_) ^ ((row_ & 7) << 4))) = h_;         \
    row_ += 32;                                                                  \
    h_[0]=(_Float16)r1a.x; h_[1]=(_Float16)r1a.y; h_[2]=(_Float16)r1a.z; h_[3]=(_Float16)r1a.w; \
    h_[4]=(_Float16)r1b.x; h_[5]=(_Float16)r1b.y; h_[6]=(_Float16)r1b.z; h_[7]=(_Float16)r1b.w; \
    *(half8*)(tl[bf_] + ((row_ * 256 + c16_) ^ ((row_ & 7) << 4))) = h_;         \
  }

  LOADR(first);
  WRITEB(0);
  __syncthreads();
  int buf = 0;

  for (int i = first; i < last; ++i) {
    const bool more = (i + 1 < last);
    if (more) LOADR(i + 1);        // issue next-tile loads early (T14)

    // compute tile i from tl[buf]
    f32x4 ag[4] = {}, af[4] = {};
#pragma unroll
    for (int ks = 0; ks < 4; ++ks) {
#pragma unroll
      for (int mi = 0; mi < 4; ++mi) {
        int r = mi * 16 + lc;
        half8 A = *(half8*)(tl[buf] + ((r * 256 + ks * 64 + q * 16) ^ ((r & 7) << 4)));
        ag[mi] = __builtin_amdgcn_mfma_f32_16x16x32_f16(A, Bg[ks], ag[mi], 0, 0, 0);
        af[mi] = __builtin_amdgcn_mfma_f32_16x16x32_f16(A, Bf[ks], af[mi], 0, 0, 0);
      }
    }

    // epilogue: P = sigm(gate)*filt, f16, original order (col fixed per lane)
    _Float16* Pc = P + (size_t)i * 64 * 128 + col;
#pragma unroll
    for (int mi = 0; mi < 4; ++mi) {
#pragma unroll
      for (int rr = 0; rr < 4; ++rr) {
        int el = mi * 16 + q * 4 + rr;
        float pv = sigm(ag[mi][rr] + bgv) * (af[mi][rr] + bfv);
        Pc[(size_t)el * 128] = (_Float16)pv;
      }
    }

    if (more) WRITEB(buf ^ 1);     // vmcnt wait folds here via data dep
    __syncthreads();
    buf ^= 1;
  }
#undef LOADR
#undef WRITEB
}

// ---------- E2: CSR per-src wave gather-reduce, fused BN+ReLU ----------
__global__ __launch_bounds__(256) void e2_kernel(
    const _Float16* __restrict__ P, const int2* __restrict__ sed,
    const unsigned* __restrict__ cstart, const unsigned* __restrict__ cnt,
    const _Float16* __restrict__ nh16,
    const float* __restrict__ gamma, const float* __restrict__ beta,
    const float* __restrict__ mean, const float* __restrict__ var,
    float* __restrict__ out) {
  int s = blockIdx.x * 4 + (threadIdx.x >> 6);
  if (s >= NN) return;
  const int lane = threadIdx.x & 63;
  const int c = lane * 2;

  const unsigned start = cstart[s];
  const int deg = (int)cnt[s];
  const unsigned end = start + (unsigned)deg;

  const _Float16* __restrict__ Pc = P + c;
  const _Float16* __restrict__ Nc = nh16 + c;

  float a0 = 0.0f, a1 = 0.0f;
  unsigned p = start;
  for (; p + 4 <= end; p += 4) {
    int2 e0 = sed[p], e1 = sed[p + 1], e2 = sed[p + 2], e3 = sed[p + 3];
    half2v P0 = *(const half2v*)(Pc + (size_t)e0.y * 128);
    half2v P1 = *(const half2v*)(Pc + (size_t)e1.y * 128);
    half2v P2 = *(const half2v*)(Pc + (size_t)e2.y * 128);
    half2v P3 = *(const half2v*)(Pc + (size_t)e3.y * 128);
    half2v N0 = *(const half2v*)(Nc + (size_t)e0.x * 128);
    half2v N1 = *(const half2v*)(Nc + (size_t)e1.x * 128);
    half2v N2 = *(const half2v*)(Nc + (size_t)e2.x * 128);
    half2v N3 = *(const half2v*)(Nc + (size_t)e3.x * 128);
    a0 += (float)P0[0] * (float)N0[0]; a1 += (float)P0[1] * (float)N0[1];
    a0 += (float)P1[0] * (float)N1[0]; a1 += (float)P1[1] * (float)N1[1];
    a0 += (float)P2[0] * (float)N2[0]; a1 += (float)P2[1] * (float)N2[1];
    a0 += (float)P3[0] * (float)N3[0]; a1 += (float)P3[1] * (float)N3[1];
  }
  for (; p < end; ++p) {
    int2 e = sed[p];
    half2v Pp = *(const half2v*)(Pc + (size_t)e.y * 128);
    half2v Np = *(const half2v*)(Nc + (size_t)e.x * 128);
    a0 += (float)Pp[0] * (float)Np[0];
    a1 += (float)Pp[1] * (float)Np[1];
  }

  float inv = deg > 0 ? 1.0f / (float)deg : 0.0f;
  half2v H = *(const half2v*)(Nc + (size_t)s * 128);
  float x0 = (float)H[0] + a0 * inv;
  float x1 = (float)H[1] + a1 * inv;
  float sc0 = rsqrtf(var[c] + 0.001f) * gamma[c];
  float sc1 = rsqrtf(var[c + 1] + 0.001f) * gamma[c + 1];
  float v0 = (x0 - mean[c]) * sc0 + beta[c];
  float v1 = (x1 - mean[c + 1]) * sc1 + beta[c + 1];
  float2 o;
  o.x = fmaxf(v0, 0.0f);
  o.y = fmaxf(v1, 0.0f);
  *(float2*)(out + (size_t)s * 128 + c) = o;
}

extern "C" void kernel_launch(void* const* d_in, const int* in_sizes, int n_in,
                              void* d_out, int out_size, void* d_ws, size_t ws_size,
                              hipStream_t stream) {
  const float* nf    = (const float*)d_in[0];
  const float* ef    = (const float*)d_in[1];
  const float* Wn    = (const float*)d_in[2];
  const float* bn    = (const float*)d_in[3];
  const float* Wg    = (const float*)d_in[4];
  const float* bg    = (const float*)d_in[5];
  const float* Wf    = (const float*)d_in[6];
  const float* bf    = (const float*)d_in[7];
  const float* gamma = (const float*)d_in[8];
  const float* beta  = (const float*)d_in[9];
  const float* mean  = (const float*)d_in[10];
  const float* var   = (const float*)d_in[11];
  const int*   eidx  = (const int*)d_in[12];
  float* out = (float*)d_out;
  char* ws = (char*)d_ws;

  _Float16* nh16   = (_Float16*)(ws + 0);            //  12,800,000
  _Float16* P16    = (_Float16*)(ws + 12800000);     // 204,800,000
  unsigned* cnt    = (unsigned*)(ws + 217600000);    //     200,000
  unsigned* cstart = (unsigned*)(ws + 217800000);    //     200,000
  unsigned* cursor = (unsigned*)(ws + 218000000);    //     200,000
  _Float16* wt     = (_Float16*)(ws + 218200000);    //      98,304
  int2*     sed    = (int2*)(ws + 218300000);        //   6,400,000  -> end 224,700,000

  hipMemsetAsync(cnt, 0, 200000, stream);

  prepw_kernel<<<3, 256, 0, stream>>>(Wn, Wg, Wf, wt);
  hist_kernel<<<NE / 256, 256, 0, stream>>>(eidx, cnt);
  scan_kernel<<<1, 1024, 0, stream>>>(cnt, cursor, cstart);
  scatter_kernel<<<NE / 256, 256, 0, stream>>>(eidx, cursor, sed);
  node_kernel<<<(NN + 255) / 256, 512, 0, stream>>>(nf, wt, bn, nh16);
  e1_kernel<<<E1B, 512, 0, stream>>>(ef, wt + 16384, wt + 32768, bg, bf, P16);
  e2_kernel<<<(NN + 3) / 4, 256, 0, stream>>>(P16, sed, cstart, cnt, nh16,
                                              gamma, beta, mean, var, out);
}